// Round 15
// baseline (538.452 us; speedup 1.0000x reference)
//
#include <hip/hip_runtime.h>

typedef __bf16 bf16x8 __attribute__((ext_vector_type(8)));
typedef __bf16 bf16x4 __attribute__((ext_vector_type(4)));
typedef float  f32x4  __attribute__((ext_vector_type(4)));

#define MFMA16(a,b,c) __builtin_amdgcn_mfma_f32_16x16x32_bf16((a),(b),(c),0,0,0)

constexpr int B_ = 256, T_ = 200, DM = 2048, DK = 128;
constexpr int VT_STRIDE = 208;      // Vt[b][v][t], t padded 200->208

// ws layout (bytes)
constexpr size_t OFF_W = 0;                       // Wcat bf16 [384][2048] = 1,572,864
constexpr size_t OFF_Q = 1572864;                 // Q bf16 [51200][128] = 13,107,200
constexpr size_t OFF_K = OFF_Q + 13107200;        // K bf16 [51200][128]
constexpr size_t OFF_V = OFF_K + 13107200;        // Vt bf16 [256][128][208] = 13,631,488

#define GLOAD_LDS16(G, L)                                                     \
  __builtin_amdgcn_global_load_lds(                                           \
      (const __attribute__((address_space(1))) void*)(G),                     \
      (__attribute__((address_space(3))) void*)(L), 16, 0, 0)

// ---------------- weight conversion: Wq|Wk|Wv fp32 -> Wcat bf16 [384][2048] ----------------
__global__ __launch_bounds__(256) void wconv_kernel(const float* __restrict__ Wq,
                                                    const float* __restrict__ Wk,
                                                    const float* __restrict__ Wv,
                                                    __bf16* __restrict__ Wcat) {
  int idx = (blockIdx.x * 256 + threadIdx.x) * 4;   // < 384*2048 = 786432
  int sel = idx >> 18;                              // /262144 -> 0,1,2
  const float* base = (sel == 0) ? Wq : (sel == 1) ? Wk : Wv;
  float4 f = *(const float4*)(base + (idx - (sel << 18)));
  bf16x4 o;
  o[0] = (__bf16)f.x; o[1] = (__bf16)f.y; o[2] = (__bf16)f.z; o[3] = (__bf16)f.w;
  *(bf16x4*)(Wcat + idx) = o;
}

// ---------------- batch-fused QKV projection: one block per batch, ZERO barriers ----------------
// Block = batch b, 512 threads = 8 waves. Wave w owns output cols [w*48, w*48+48).
// Nothing is shared between waves -> no __syncthreads anywhere:
//  * B (Wcat slice) staged into WAVE-PRIVATE LDS (3 KB x 3 bufs per wave) via
//    global_load_lds; same-wave produce/consume ordered by COUNTED vmcnt only.
//    Steady wait vmcnt(30) = retire exactly tile t (issued 2 bodies = ~2 tiles ago).
//  * A (q rows, fp32) direct-global into double reg sets; all 8 waves read the same
//    64-row slice -> L1 serves the 8x redundancy; cvt fp32->bf16 at use (VALU pipe,
//    overlaps MFMA across waves). q is HBM-read exactly once chip-wide.
// Per wave K-step: 3 gload_lds + 8 f32x4 + 3 ds_read_b128 + 12 MFMA (16x16x32).
// rt loop: 4 row-tiles of 64 (last clamped to rows 192..199).
// B LDS swizzle: slot s holds logical chunk (s&3)^((s>>2)&3); read phys = lhi^(llo&3).
__global__ __launch_bounds__(512) void qkv_kernel(const float* __restrict__ q,
                                                  const __bf16* __restrict__ Wcat,
                                                  __bf16* __restrict__ Qo,
                                                  __bf16* __restrict__ Ko,
                                                  __bf16* __restrict__ Vt) {
  __shared__ alignas(16) char bsm[73728];   // 8 waves x 3 bufs x 3072 B (wave-private)

  const int tid  = threadIdx.x;
  const int lane = tid & 63;
  const int w    = tid >> 6;
  const int lhi  = lane >> 4, llo = lane & 15;
  const int b    = blockIdx.x;
  const int n0   = w * 48;

  // B staging source: row = n0 + (lane>>2) + 16r, logical chunk = (lane&3)^((lane>>2)&3)
  const __bf16* bgbase = Wcat + (size_t)(n0 + (lane >> 2)) * DM
                              + (((lane & 3) ^ ((lane >> 2) & 3)) << 3);
  char* const bls = bsm + w * 9216;
  // B frag read: row = j*16+llo, phys chunk = lhi ^ (llo&3)
  const int bro = llo * 64 + ((lhi ^ (llo & 3)) << 4);   // + j*1024

  const float* const abase = q + (size_t)b * T_ * DM + lhi * 8;

  f32x4 a0[8], a1[8];     // A double set (all indices compile-time in unrolled loops)
  f32x4 acc[4][3];

#define VMW(N) asm volatile("s_waitcnt vmcnt(" #N ")" ::: "memory")

#define B_ISSUE(BUF, KS)                                                      \
  { char* d_ = bls + (BUF) * 3072 + lane * 16;                                \
    const __bf16* s_ = bgbase + (KS);                                         \
    GLOAD_LDS16(s_, d_);                                                      \
    GLOAD_LDS16(s_ + (size_t)16 * DM, d_ + 1024);                             \
    GLOAD_LDS16(s_ + (size_t)32 * DM, d_ + 2048); }

#define A_ISSUE(SET, KS)                                                      \
  { _Pragma("unroll")                                                         \
    for (int i_ = 0; i_ < 4; ++i_) {                                          \
      SET[2 * i_]     = *(const f32x4*)(ap[i_] + (KS));                       \
      SET[2 * i_ + 1] = *(const f32x4*)(ap[i_] + (KS) + 4); } }

#define COMPUTE(BUF, SET)                                                     \
  { const char* lb_ = bls + (BUF) * 3072;                                     \
    bf16x8 bf0_ = *(const bf16x8*)(lb_ + bro);                                \
    bf16x8 bf1_ = *(const bf16x8*)(lb_ + bro + 1024);                         \
    bf16x8 bf2_ = *(const bf16x8*)(lb_ + bro + 2048);                         \
    _Pragma("unroll")                                                         \
    for (int i_ = 0; i_ < 4; ++i_) {                                          \
      bf16x8 af_;                                                             \
      af_[0]=(__bf16)SET[2*i_][0];   af_[1]=(__bf16)SET[2*i_][1];             \
      af_[2]=(__bf16)SET[2*i_][2];   af_[3]=(__bf16)SET[2*i_][3];             \
      af_[4]=(__bf16)SET[2*i_+1][0]; af_[5]=(__bf16)SET[2*i_+1][1];           \
      af_[6]=(__bf16)SET[2*i_+1][2]; af_[7]=(__bf16)SET[2*i_+1][3];           \
      acc[i_][0] = MFMA16(af_, bf0_, acc[i_][0]);                             \
      acc[i_][1] = MFMA16(af_, bf1_, acc[i_][1]);                             \
      acc[i_][2] = MFMA16(af_, bf2_, acc[i_][2]); } }

  for (int rt = 0; rt < 4; ++rt) {
    const float* ap[4];
#pragma unroll
    for (int i = 0; i < 4; ++i) {
      int t = rt * 64 + i * 16 + llo;
      if (t > T_ - 1) t = T_ - 1;                  // clamp (rows >= 200 computed, not stored)
      ap[i] = abase + (size_t)t * DM;
    }
#pragma unroll
    for (int i = 0; i < 4; ++i)
#pragma unroll
      for (int j = 0; j < 3; ++j) acc[i][j] = {0.f, 0.f, 0.f, 0.f};

    // prologue: B(0)->b0, B(1)->b1, A(0)->a0   (14 loads in flight)
    B_ISSUE(0, 0);
    B_ISSUE(1, 32);
    A_ISSUE(a0, 0);
    // body T=0 (cur b0): after-B(0) = 22
    B_ISSUE(2, 2 * 32); A_ISSUE(a1, 1 * 32); VMW(22); COMPUTE(0, a0);
    // bodies T = 1..60 (10 x 6); steady: after-B(T) = 30
    for (int tp = 0; tp < 10; ++tp) {
      const int t6 = tp * 6;
      B_ISSUE(0, (t6 + 3) * 32); A_ISSUE(a0, (t6 + 2) * 32); VMW(30); COMPUTE(1, a1);
      B_ISSUE(1, (t6 + 4) * 32); A_ISSUE(a1, (t6 + 3) * 32); VMW(30); COMPUTE(2, a0);
      B_ISSUE(2, (t6 + 5) * 32); A_ISSUE(a0, (t6 + 4) * 32); VMW(30); COMPUTE(0, a1);
      B_ISSUE(0, (t6 + 6) * 32); A_ISSUE(a1, (t6 + 5) * 32); VMW(30); COMPUTE(1, a0);
      B_ISSUE(1, (t6 + 7) * 32); A_ISSUE(a0, (t6 + 6) * 32); VMW(30); COMPUTE(2, a1);
      B_ISSUE(2, (t6 + 8) * 32); A_ISSUE(a1, (t6 + 7) * 32); VMW(30); COMPUTE(0, a0);
    }
    // T=61 (cur b1): issues B(63), A(62)
    B_ISSUE(0, 63 * 32); A_ISSUE(a0, 62 * 32); VMW(30); COMPUTE(1, a1);
    // T=62 (cur b2): issues A(63); after-B(62) = 27
    A_ISSUE(a1, 63 * 32); VMW(27); COMPUTE(2, a0);
    // T=63 (cur b0): after-B(63) = 16
    VMW(16); COMPUTE(0, a1);

    // epilogue: write Q/K/Vt for this row tile
#pragma unroll
    for (int i = 0; i < 4; ++i) {
#pragma unroll
      for (int rr = 0; rr < 4; ++rr) {
        int t = rt * 64 + i * 16 + lhi * 4 + rr;
        if (t < T_) {
#pragma unroll
          for (int j = 0; j < 3; ++j) {
            int col = n0 + j * 16 + llo;
            __bf16 v = (__bf16)acc[i][j][rr];
            if (col < 128)       Qo[((size_t)b * T_ + t) * DK + col] = v;
            else if (col < 256)  Ko[((size_t)b * T_ + t) * DK + (col - 128)] = v;
            else                 Vt[((size_t)b * DK + (col - 256)) * VT_STRIDE + t] = v;
          }
        }
      }
    }
    VMW(0);   // drain stores so next rt's counted waits see a clean queue
  }
#undef VMW
#undef B_ISSUE
#undef A_ISSUE
#undef COMPUTE
}

// ---------------- attention: one WG per (batch, 64-query block), templated on block ----------------
template <int QB>
__global__ __launch_bounds__(256, 1) void attn_kernel(const __bf16* __restrict__ Qg,
                                                      const __bf16* __restrict__ Kg,
                                                      const __bf16* __restrict__ Vt,
                                                      const int* __restrict__ padm,
                                                      float* __restrict__ out) {
  constexpr int Q0     = QB * 64;
  constexpr int KMAX   = (Q0 + 64 < T_) ? (Q0 + 64) : T_;   // 64,128,192,200 (causal bound)
  constexpr int KTILES = (KMAX + 15) / 16;                  // 4,8,12,13
  constexpr int KCC    = (KMAX + 31) / 32;                  // 2,4,6,7
  constexpr int KT16   = KTILES * 16;                       // 64,128,192,208
  constexpr int KP     = KCC * 32;                          // 64,128,192,224
  constexpr int VS     = KP + 8;                            // padded stride (bank spread)

  __shared__ __bf16 sK[KT16][136];
  __shared__ __bf16 sV[128][VS];       // V^T: [v][t]
  __shared__ __bf16 sP[4][16][VS];     // per-wave P transpose buffer
  __shared__ float  sMask[KT16];

  const int tid  = threadIdx.x;
  const int lane = tid & 63;
  const int w    = tid >> 6;
  const int b    = blockIdx.x;
  const int lhi  = lane >> 4, llo = lane & 15;

  // additive key mask: 0 valid, -1e30 for pad / t>=KMAX
  for (int t = tid; t < KT16; t += 256) {
    float mv = -1e30f;
    if (t < KMAX && padm[b * T_ + t] == 0) mv = 0.0f;
    sMask[t] = mv;
  }
  // stage K rows [0, KT16) (rows >= T_ clamped; they get masked anyway)
  for (int cid = tid; cid < KT16 * 16; cid += 256) {
    int t = cid >> 4, c = (cid & 15) * 8;
    int tg = (t < T_) ? t : (T_ - 1);
    *(bf16x8*)&sK[t][c] = *(const bf16x8*)(Kg + ((size_t)b * T_ + tg) * DK + c);
  }
  // stage V^T: [128][KP), zeros beyond Vt's 208 columns
  {
    constexpr int NCH = KP / 8;
    for (int cid = tid; cid < 128 * NCH; cid += 256) {
      int v = cid / NCH, t0 = (cid % NCH) * 8;
      bf16x8 val;
      if (t0 < VT_STRIDE) {
        val = *(const bf16x8*)(Vt + ((size_t)b * DK + v) * VT_STRIDE + t0);
      } else {
#pragma unroll
        for (int jz = 0; jz < 8; ++jz) val[jz] = (__bf16)0.0f;
      }
      *(bf16x8*)&sV[v][t0] = val;
    }
  }
  // zero P pad columns [KT16, KP) (only QB==3: 208..224)
  if constexpr (KT16 < KP) {
    constexpr int NC = (KP - KT16) / 8;
    for (int idx = tid; idx < 4 * 16 * NC; idx += 256) {
      int ww = idx / (16 * NC);
      int rem = idx % (16 * NC);
      int row = rem / NC, cc = (rem % NC) * 8;
      bf16x8 z;
#pragma unroll
      for (int jz = 0; jz < 8; ++jz) z[jz] = (__bf16)0.0f;
      *(bf16x8*)&sP[ww][row][KT16 + cc] = z;
    }
  }
  __syncthreads();

  // Q fragments in registers (A-frag: row = llo, k-chunk = lhi)
  const int q0w = Q0 + w * 16;
  bf16x8 qf[4];
  {
    int qrow = q0w + llo;
    if (qrow > T_ - 1) qrow = T_ - 1;
    const __bf16* qp = Qg + ((size_t)b * T_ + qrow) * DK + lhi * 8;
#pragma unroll
    for (int kk = 0; kk < 4; ++kk) qf[kk] = *(const bf16x8*)(qp + kk * 32);
  }

  // scores: S[16q x KT16] per wave, kept in registers
  float sc[KTILES][4];
  const float scale = 0.022097086912079608f;   // 1/sqrt(2048)
#pragma unroll
  for (int tt = 0; tt < KTILES; ++tt) {
    f32x4 s = {0.f, 0.f, 0.f, 0.f};
    const __bf16* kp = &sK[tt * 16 + llo][lhi * 8];
#pragma unroll
    for (int kk = 0; kk < 4; ++kk) {
      bf16x8 kf = *(const bf16x8*)(kp + kk * 32);
      s = MFMA16(qf[kk], kf, s);
    }
    const int t = tt * 16 + llo;
    const float madd = sMask[t];
#pragma unroll
    for (int r = 0; r < 4; ++r) {
      int qq = q0w + lhi * 4 + r;               // C layout: row = lhi*4+r, col = llo
      float v = fmaf(s[r], scale, madd);
      sc[tt][r] = (t > qq) ? -1e30f : v;        // overwrite-style causal mask (NaN-safe)
    }
  }

  // row softmax: reduce across the 16-lane col group per accumulator row
#pragma unroll
  for (int r = 0; r < 4; ++r) {
    float mm = -3e38f;
#pragma unroll
    for (int tt = 0; tt < KTILES; ++tt) mm = fmaxf(mm, sc[tt][r]);
#pragma unroll
    for (int off = 1; off < 16; off <<= 1) mm = fmaxf(mm, __shfl_xor(mm, off));
    float ss = 0.f;
#pragma unroll
    for (int tt = 0; tt < KTILES; ++tt) { float e = __expf(sc[tt][r] - mm); sc[tt][r] = e; ss += e; }
#pragma unroll
    for (int off = 1; off < 16; off <<= 1) ss += __shfl_xor(ss, off);
    float inv = 1.0f / ss;
#pragma unroll
    for (int tt = 0; tt < KTILES; ++tt) sc[tt][r] *= inv;
  }

  // P -> LDS (transpose through memory for the PV A-fragment)
#pragma unroll
  for (int tt = 0; tt < KTILES; ++tt) {
    int t = tt * 16 + llo;
#pragma unroll
    for (int r = 0; r < 4; ++r) sP[w][lhi * 4 + r][t] = (__bf16)sc[tt][r];
  }
  __syncthreads();

  // PV: out[16q x 128v] = P[16 x KP] @ V[KP x 128]
  f32x4 oacc[8];
#pragma unroll
  for (int vt = 0; vt < 8; ++vt) oacc[vt] = {0.f, 0.f, 0.f, 0.f};
#pragma unroll
  for (int kc = 0; kc < KCC; ++kc) {
    bf16x8 pa = *(const bf16x8*)&sP[w][llo][kc * 32 + lhi * 8];
#pragma unroll
    for (int vt = 0; vt < 8; ++vt) {
      bf16x8 vb = *(const bf16x8*)&sV[vt * 16 + llo][kc * 32 + lhi * 8];
      oacc[vt] = MFMA16(pa, vb, oacc[vt]);
    }
  }

  // write fp32 output
#pragma unroll
  for (int vt = 0; vt < 8; ++vt) {
#pragma unroll
    for (int r = 0; r < 4; ++r) {
      int qq = q0w + lhi * 4 + r;
      if (qq < T_) out[((size_t)b * T_ + qq) * DK + vt * 16 + llo] = oacc[vt][r];
    }
  }
}

extern "C" void kernel_launch(void* const* d_in, const int* in_sizes, int n_in,
                              void* d_out, int out_size, void* d_ws, size_t ws_size,
                              hipStream_t stream) {
  const float* q    = (const float*)d_in[0];
  const int*   padm = (const int*)d_in[1];
  const float* Wq   = (const float*)d_in[2];
  const float* Wk   = (const float*)d_in[3];
  const float* Wv   = (const float*)d_in[4];
  float* out        = (float*)d_out;

  char* ws = (char*)d_ws;
  __bf16* Wcat = (__bf16*)(ws + OFF_W);
  __bf16* Qb   = (__bf16*)(ws + OFF_Q);
  __bf16* Kb   = (__bf16*)(ws + OFF_K);
  __bf16* Vtb  = (__bf16*)(ws + OFF_V);

  wconv_kernel<<<768, 256, 0, stream>>>(Wq, Wk, Wv, Wcat);
  qkv_kernel<<<256, 512, 0, stream>>>(q, Wcat, Qb, Kb, Vtb);
  attn_kernel<0><<<256, 256, 0, stream>>>(Qb, Kb, Vtb, padm, out);
  attn_kernel<1><<<256, 256, 0, stream>>>(Qb, Kb, Vtb, padm, out);
  attn_kernel<2><<<256, 256, 0, stream>>>(Qb, Kb, Vtb, padm, out);
  attn_kernel<3><<<256, 256, 0, stream>>>(Qb, Kb, Vtb, padm, out);
}

// Round 16
// 255.336 us; speedup vs baseline: 2.1088x; 2.1088x over previous
//
#include <hip/hip_runtime.h>

typedef __bf16 bf16x8 __attribute__((ext_vector_type(8)));
typedef __bf16 bf16x4 __attribute__((ext_vector_type(4)));
typedef float  f32x4  __attribute__((ext_vector_type(4)));

#define MFMA16(a,b,c) __builtin_amdgcn_mfma_f32_16x16x32_bf16((a),(b),(c),0,0,0)

constexpr int B_ = 256, T_ = 200, DM = 2048, DK = 128;
constexpr int VT_STRIDE = 208;      // Vt[b][v][t], t padded 200->208

// ws layout (bytes)
constexpr size_t OFF_W = 0;                       // Wcat bf16 [384][2048] = 1,572,864
constexpr size_t OFF_Q = 1572864;                 // Q bf16 [51200][128] = 13,107,200
constexpr size_t OFF_K = OFF_Q + 13107200;        // K bf16 [51200][128]
constexpr size_t OFF_V = OFF_K + 13107200;        // Vt bf16 [256][128][208] = 13,631,488

#define GLOAD_LDS16(G, L)                                                     \
  __builtin_amdgcn_global_load_lds(                                           \
      (const __attribute__((address_space(1))) void*)(G),                     \
      (__attribute__((address_space(3))) void*)(L), 16, 0, 0)

// ---------------- weight conversion: Wq|Wk|Wv fp32 -> Wcat bf16 [384][2048] ----------------
__global__ __launch_bounds__(256) void wconv_kernel(const float* __restrict__ Wq,
                                                    const float* __restrict__ Wk,
                                                    const float* __restrict__ Wv,
                                                    __bf16* __restrict__ Wcat) {
  int idx = (blockIdx.x * 256 + threadIdx.x) * 4;   // < 384*2048 = 786432
  int sel = idx >> 18;                              // /262144 -> 0,1,2
  const float* base = (sel == 0) ? Wq : (sel == 1) ? Wk : Wv;
  float4 f = *(const float4*)(base + (idx - (sel << 18)));
  bf16x4 o;
  o[0] = (__bf16)f.x; o[1] = (__bf16)f.y; o[2] = (__bf16)f.z; o[3] = (__bf16)f.w;
  *(bf16x4*)(Wcat + idx) = o;
}

// ---------------- projection GEMM: C[51200][384] = q(fp32->bf16) @ Wcat^T ----------------
// R16 = R10/R13's proven-simplest loop (all global_load_lds staging, cvt fp32->bf16 at
// frag read, plain 2-__syncthreads single-buffer K-loop, XCD-triplet job map) with the
// block SCALED UP to amortize per-step overhead: BM=256, BN=128, BK=64, 512 threads =
// 8 waves (4m x 2n, wave tile 64x64, acc=64 AGPR, 32 MFMA/wave/step = m97 density).
// Total block-steps halve vs R10 (600 blocks x 32 steps); per-step overhead amortized
// over 2x work. LDS 80 KB -> 2 blocks/CU; simple structure keeps VGPR ~116 -> 4
// waves/SIMD -> 16 waves/CU; the co-resident block hides the stage drain (m114).
// Both-sides XOR swizzle (A chunk c^(row&15), B chunk c^(row&7)) -> frag reads 2-way.
__global__ __launch_bounds__(512) void proj_kernel(const float* __restrict__ q,
                                                   const __bf16* __restrict__ Wcat,
                                                   __bf16* __restrict__ Qo,
                                                   __bf16* __restrict__ Ko,
                                                   __bf16* __restrict__ Vt) {
  __shared__ alignas(16) char smem[81920];   // A fp32 [256][64] @0 (64 KB), B bf16 [128][64] @65536 (16 KB)

  const int tid  = threadIdx.x;
  const int lane = tid & 63;
  const int w    = tid >> 6;
  const int wm   = w >> 1, wn = w & 1;       // 4 waves over M, 2 over N
  const int lhi  = lane >> 4, llo = lane & 15;

  // XCD-grouped job mapping (600 = 8 XCDs x 75 jobs; 75 % 3 == 0 -> triplets never straddle)
  const int d  = blockIdx.x;
  const int jj = (d & 7) * 75 + (d >> 3);
  const int mp = jj / 3, nb = jj - mp * 3;
  const int m0 = mp * 256;
  const int col0 = nb * 128;

  f32x4 acc[4][4];
#pragma unroll
  for (int i = 0; i < 4; ++i)
#pragma unroll
    for (int j = 0; j < 4; ++j) acc[i][j] = {0.f, 0.f, 0.f, 0.f};

  // A staging: 8 rounds of 32 rows; thread -> row=(tid>>4)+32r (16 lanes cover the full
  // 256-B fp32 row), src chunk = (tid&15)^((tid>>4)&15)   (round-invariant: 32r&15==0)
  const float* agbase = q + (size_t)(m0 + (tid >> 4)) * DM
                          + (((tid & 15) ^ ((tid >> 4) & 15)) << 2);
  // B staging: 2 rounds of 64 rows; row=(tid>>3)+64r (8 lanes per 128-B row),
  // src chunk = (tid&7)^((tid>>3)&7)   (round-invariant: 64r&7==0)
  const __bf16* bgbase = Wcat + (size_t)(col0 + (tid >> 3)) * DM
                              + (((tid & 7) ^ ((tid >> 3) & 7)) << 3);

  constexpr int NK = DM / 64;   // 32 K-steps
  for (int t = 0; t < NK; ++t) {
    const int k0 = t * 64;
#pragma unroll
    for (int r = 0; r < 8; ++r)
      GLOAD_LDS16(agbase + (size_t)r * 32 * DM + k0, smem + tid * 16 + r * 8192);
#pragma unroll
    for (int r = 0; r < 2; ++r)
      GLOAD_LDS16(bgbase + (size_t)r * 64 * DM + k0, smem + 65536 + tid * 16 + r * 8192);
    __syncthreads();           // tile t visible

#pragma unroll
    for (int kk = 0; kk < 2; ++kk) {
      bf16x8 af[4];
#pragma unroll
      for (int i = 0; i < 4; ++i) {
        const int row = wm * 64 + i * 16 + llo;          // row & 15 == llo
        const int c0 = kk * 8 + lhi * 2;
        f32x4 u = *(const f32x4*)(smem + row * 256 + (((c0 ^ llo) & 15) << 4));
        f32x4 v = *(const f32x4*)(smem + row * 256 + ((((c0 + 1) ^ llo) & 15) << 4));
        af[i][0]=(__bf16)u[0]; af[i][1]=(__bf16)u[1]; af[i][2]=(__bf16)u[2]; af[i][3]=(__bf16)u[3];
        af[i][4]=(__bf16)v[0]; af[i][5]=(__bf16)v[1]; af[i][6]=(__bf16)v[2]; af[i][7]=(__bf16)v[3];
      }
      bf16x8 bfr[4];
#pragma unroll
      for (int j = 0; j < 4; ++j) {
        const int row = wn * 64 + j * 16 + llo;          // row & 7 == llo & 7
        const int c = kk * 4 + lhi;
        bfr[j] = *(const bf16x8*)(smem + 65536 + row * 128 + (((c ^ (llo & 7)) & 7) << 4));
      }
#pragma unroll
      for (int i = 0; i < 4; ++i)
#pragma unroll
        for (int j = 0; j < 4; ++j) acc[i][j] = MFMA16(af[i], bfr[j], acc[i][j]);
    }
    if (t + 1 < NK) __syncthreads();   // protect single buffer before next stage
  }

  // epilogue: nb selects destination (block-uniform branch)
  if (nb == 0) {
#pragma unroll
    for (int i = 0; i < 4; ++i)
#pragma unroll
      for (int r = 0; r < 4; ++r) {
        int row = m0 + wm * 64 + i * 16 + lhi * 4 + r;
#pragma unroll
        for (int j = 0; j < 4; ++j)
          Qo[(size_t)row * DK + wn * 64 + j * 16 + llo] = (__bf16)acc[i][j][r];
      }
  } else if (nb == 1) {
#pragma unroll
    for (int i = 0; i < 4; ++i)
#pragma unroll
      for (int r = 0; r < 4; ++r) {
        int row = m0 + wm * 64 + i * 16 + lhi * 4 + r;
#pragma unroll
        for (int j = 0; j < 4; ++j)
          Ko[(size_t)row * DK + wn * 64 + j * 16 + llo] = (__bf16)acc[i][j][r];
      }
  } else {
#pragma unroll
    for (int i = 0; i < 4; ++i)
#pragma unroll
      for (int r = 0; r < 4; ++r) {
        int row = m0 + wm * 64 + i * 16 + lhi * 4 + r;
        int b = row / 200;
        int t = row - b * 200;
#pragma unroll
        for (int j = 0; j < 4; ++j) {
          int col = wn * 64 + j * 16 + llo;
          Vt[((size_t)b * DK + col) * VT_STRIDE + t] = (__bf16)acc[i][j][r];
        }
      }
  }
}

// ---------------- attention: one WG per (batch, 64-query block), templated on block ----------------
template <int QB>
__global__ __launch_bounds__(256, 1) void attn_kernel(const __bf16* __restrict__ Qg,
                                                      const __bf16* __restrict__ Kg,
                                                      const __bf16* __restrict__ Vt,
                                                      const int* __restrict__ padm,
                                                      float* __restrict__ out) {
  constexpr int Q0     = QB * 64;
  constexpr int KMAX   = (Q0 + 64 < T_) ? (Q0 + 64) : T_;   // 64,128,192,200 (causal bound)
  constexpr int KTILES = (KMAX + 15) / 16;                  // 4,8,12,13
  constexpr int KCC    = (KMAX + 31) / 32;                  // 2,4,6,7
  constexpr int KT16   = KTILES * 16;                       // 64,128,192,208
  constexpr int KP     = KCC * 32;                          // 64,128,192,224
  constexpr int VS     = KP + 8;                            // padded stride (bank spread)

  __shared__ __bf16 sK[KT16][136];
  __shared__ __bf16 sV[128][VS];       // V^T: [v][t]
  __shared__ __bf16 sP[4][16][VS];     // per-wave P transpose buffer
  __shared__ float  sMask[KT16];

  const int tid  = threadIdx.x;
  const int lane = tid & 63;
  const int w    = tid >> 6;
  const int b    = blockIdx.x;
  const int lhi  = lane >> 4, llo = lane & 15;

  // additive key mask: 0 valid, -1e30 for pad / t>=KMAX
  for (int t = tid; t < KT16; t += 256) {
    float mv = -1e30f;
    if (t < KMAX && padm[b * T_ + t] == 0) mv = 0.0f;
    sMask[t] = mv;
  }
  // stage K rows [0, KT16) (rows >= T_ clamped; they get masked anyway)
  for (int cid = tid; cid < KT16 * 16; cid += 256) {
    int t = cid >> 4, c = (cid & 15) * 8;
    int tg = (t < T_) ? t : (T_ - 1);
    *(bf16x8*)&sK[t][c] = *(const bf16x8*)(Kg + ((size_t)b * T_ + tg) * DK + c);
  }
  // stage V^T: [128][KP), zeros beyond Vt's 208 columns
  {
    constexpr int NCH = KP / 8;
    for (int cid = tid; cid < 128 * NCH; cid += 256) {
      int v = cid / NCH, t0 = (cid % NCH) * 8;
      bf16x8 val;
      if (t0 < VT_STRIDE) {
        val = *(const bf16x8*)(Vt + ((size_t)b * DK + v) * VT_STRIDE + t0);
      } else {
#pragma unroll
        for (int jz = 0; jz < 8; ++jz) val[jz] = (__bf16)0.0f;
      }
      *(bf16x8*)&sV[v][t0] = val;
    }
  }
  // zero P pad columns [KT16, KP) (only QB==3: 208..224)
  if constexpr (KT16 < KP) {
    constexpr int NC = (KP - KT16) / 8;
    for (int idx = tid; idx < 4 * 16 * NC; idx += 256) {
      int ww = idx / (16 * NC);
      int rem = idx % (16 * NC);
      int row = rem / NC, cc = (rem % NC) * 8;
      bf16x8 z;
#pragma unroll
      for (int jz = 0; jz < 8; ++jz) z[jz] = (__bf16)0.0f;
      *(bf16x8*)&sP[ww][row][KT16 + cc] = z;
    }
  }
  __syncthreads();

  // Q fragments in registers (A-frag: row = llo, k-chunk = lhi)
  const int q0w = Q0 + w * 16;
  bf16x8 qf[4];
  {
    int qrow = q0w + llo;
    if (qrow > T_ - 1) qrow = T_ - 1;
    const __bf16* qp = Qg + ((size_t)b * T_ + qrow) * DK + lhi * 8;
#pragma unroll
    for (int kk = 0; kk < 4; ++kk) qf[kk] = *(const bf16x8*)(qp + kk * 32);
  }

  // scores: S[16q x KT16] per wave, kept in registers
  float sc[KTILES][4];
  const float scale = 0.022097086912079608f;   // 1/sqrt(2048)
#pragma unroll
  for (int tt = 0; tt < KTILES; ++tt) {
    f32x4 s = {0.f, 0.f, 0.f, 0.f};
    const __bf16* kp = &sK[tt * 16 + llo][lhi * 8];
#pragma unroll
    for (int kk = 0; kk < 4; ++kk) {
      bf16x8 kf = *(const bf16x8*)(kp + kk * 32);
      s = MFMA16(qf[kk], kf, s);
    }
    const int t = tt * 16 + llo;
    const float madd = sMask[t];
#pragma unroll
    for (int r = 0; r < 4; ++r) {
      int qq = q0w + lhi * 4 + r;               // C layout: row = lhi*4+r, col = llo
      float v = fmaf(s[r], scale, madd);
      sc[tt][r] = (t > qq) ? -1e30f : v;        // overwrite-style causal mask (NaN-safe)
    }
  }

  // row softmax: reduce across the 16-lane col group per accumulator row
#pragma unroll
  for (int r = 0; r < 4; ++r) {
    float mm = -3e38f;
#pragma unroll
    for (int tt = 0; tt < KTILES; ++tt) mm = fmaxf(mm, sc[tt][r]);
#pragma unroll
    for (int off = 1; off < 16; off <<= 1) mm = fmaxf(mm, __shfl_xor(mm, off));
    float ss = 0.f;
#pragma unroll
    for (int tt = 0; tt < KTILES; ++tt) { float e = __expf(sc[tt][r] - mm); sc[tt][r] = e; ss += e; }
#pragma unroll
    for (int off = 1; off < 16; off <<= 1) ss += __shfl_xor(ss, off);
    float inv = 1.0f / ss;
#pragma unroll
    for (int tt = 0; tt < KTILES; ++tt) sc[tt][r] *= inv;
  }

  // P -> LDS (transpose through memory for the PV A-fragment)
#pragma unroll
  for (int tt = 0; tt < KTILES; ++tt) {
    int t = tt * 16 + llo;
#pragma unroll
    for (int r = 0; r < 4; ++r) sP[w][lhi * 4 + r][t] = (__bf16)sc[tt][r];
  }
  __syncthreads();

  // PV: out[16q x 128v] = P[16 x KP] @ V[KP x 128]
  f32x4 oacc[8];
#pragma unroll
  for (int vt = 0; vt < 8; ++vt) oacc[vt] = {0.f, 0.f, 0.f, 0.f};
#pragma unroll
  for (int kc = 0; kc < KCC; ++kc) {
    bf16x8 pa = *(const bf16x8*)&sP[w][llo][kc * 32 + lhi * 8];
#pragma unroll
    for (int vt = 0; vt < 8; ++vt) {
      bf16x8 vb = *(const bf16x8*)&sV[vt * 16 + llo][kc * 32 + lhi * 8];
      oacc[vt] = MFMA16(pa, vb, oacc[vt]);
    }
  }

  // write fp32 output
#pragma unroll
  for (int vt = 0; vt < 8; ++vt) {
#pragma unroll
    for (int r = 0; r < 4; ++r) {
      int qq = q0w + lhi * 4 + r;
      if (qq < T_) out[((size_t)b * T_ + qq) * DK + vt * 16 + llo] = oacc[vt][r];
    }
  }
}

extern "C" void kernel_launch(void* const* d_in, const int* in_sizes, int n_in,
                              void* d_out, int out_size, void* d_ws, size_t ws_size,
                              hipStream_t stream) {
  const float* q    = (const float*)d_in[0];
  const int*   padm = (const int*)d_in[1];
  const float* Wq   = (const float*)d_in[2];
  const float* Wk   = (const float*)d_in[3];
  const float* Wv   = (const float*)d_in[4];
  float* out        = (float*)d_out;

  char* ws = (char*)d_ws;
  __bf16* Wcat = (__bf16*)(ws + OFF_W);
  __bf16* Qb   = (__bf16*)(ws + OFF_Q);
  __bf16* Kb   = (__bf16*)(ws + OFF_K);
  __bf16* Vtb  = (__bf16*)(ws + OFF_V);

  wconv_kernel<<<768, 256, 0, stream>>>(Wq, Wk, Wv, Wcat);
  proj_kernel<<<600, 512, 0, stream>>>(q, Wcat, Qb, Kb, Vtb);
  attn_kernel<0><<<256, 256, 0, stream>>>(Qb, Kb, Vtb, padm, out);
  attn_kernel<1><<<256, 256, 0, stream>>>(Qb, Kb, Vtb, padm, out);
  attn_kernel<2><<<256, 256, 0, stream>>>(Qb, Kb, Vtb, padm, out);
  attn_kernel<3><<<256, 256, 0, stream>>>(Qb, Kb, Vtb, padm, out);
}